// Round 2
// baseline (122.108 us; speedup 1.0000x reference)
//
#include <hip/hip_runtime.h>
#include <hip/hip_bf16.h>
#include <cstdint>

// LearnableUpsamplingLayer: polyphase decomposition + bf16 MFMA, pipelined.
// B=8, T=16384, C=64, F=64, filter=5, leaky 0.3.
// Polyphase: out[b,2t+p,f] = sum_taps M_p[tap][c,f] * x[t-1+tap, c]
// Even p=0: 3 taps; odd p=1: 4 taps (x out of range = 0).
// Frames 0,1 (t=0) exactly fixed up (blend[-1] leakage).

#define T_ 16384
#define TWO_T 32768
#define TM 64              // time-pairs per chunk
#define NFR 67             // staged frames per chunk: t0-1 .. t0+65
#define XSTRIDE 72         // ushorts per frame row (144B, 16B-aligned, padded)
#define NCHUNK 2048
#define GRID 512
#define CPB 4              // chunks per block (grid-stride by GRID)

typedef __bf16 bf16x8 __attribute__((ext_vector_type(8)));
typedef float  f32x4  __attribute__((ext_vector_type(4)));
typedef unsigned short u16x8 __attribute__((ext_vector_type(8)));
typedef unsigned short u16x4 __attribute__((ext_vector_type(4)));

__device__ __forceinline__ unsigned short f2bf(float f) {
    union { float f; uint32_t u; } v; v.f = f;
    uint32_t u = v.u;
    return (unsigned short)((u + 0x7FFFu + ((u >> 16) & 1u)) >> 16);
}

__device__ __forceinline__ float sigmoidf_(float z) {
    return 1.0f / (1.0f + expf(-z));
}

// ---------------- prep: build the 7 polyphase matrices as packed bf16 MFMA
// B-fragments in d_ws. Fragment (phase, ks, nt): lane l, elem i holds
// M[tap = ks>>1][c = (ks&1)*32 + (l>>4)*8 + i][n = nt*16 + (l&15)].
__global__ void lu_prep_kernel(const float* __restrict__ iw,
                               const float* __restrict__ ck,
                               unsigned short* __restrict__ bp) {
    int fi = blockIdx.x;          // 0..55
    int l  = threadIdx.x;         // 0..63
    int phase, ks, nt;
    if (fi < 24) { phase = 0; ks = fi >> 2; nt = fi & 3; }
    else         { phase = 1; ks = (fi - 24) >> 2; nt = (fi - 24) & 3; }
    int tap = ks >> 1;
    int n   = nt * 16 + (l & 15);
    int c0  = ((ks & 1) << 5) + ((l >> 4) << 3);
    u16x8 pk;
#pragma unroll
    for (int i = 0; i < 8; ++i) {
        int c = c0 + i;
        float w = sigmoidf_(iw[c]);
        float v;
        #define CK(k) ck[((k) * 64 + c) * 64 + n]
        if (phase == 0) {
            if (tap == 0)      v = CK(0) + w * CK(1);
            else if (tap == 1) v = (1.f - w) * CK(1) + CK(2) + w * CK(3);
            else               v = (1.f - w) * CK(3) + CK(4);
        } else {
            if (tap == 0)      v = w * CK(0);
            else if (tap == 1) v = (1.f - w) * CK(0) + CK(1) + w * CK(2);
            else if (tap == 2) v = (1.f - w) * CK(2) + CK(3) + w * CK(4);
            else               v = (1.f - w) * CK(4);
        }
        #undef CK
        pk[i] = f2bf(v);
    }
    *(u16x8*)(bp + (((size_t)fi * 64) + l) * 8) = pk;
}

// ---------------- main kernel ----------------
__device__ __forceinline__ void issue_loads(const float* __restrict__ x,
                                            int g, int tid, float4* ld) {
    int b  = g >> 8;
    int t0 = (g & 255) * TM;
#pragma unroll
    for (int it = 0; it < 5; ++it) {
        int idx = it * 256 + tid;
        float4 v = make_float4(0.f, 0.f, 0.f, 0.f);
        if (idx < NFR * 16) {
            int j  = idx >> 4;
            int c4 = (idx & 15) << 2;
            int gf = t0 - 1 + j;
            if (gf >= 0 && gf < T_)
                v = *(const float4*)(x + ((size_t)b * T_ + gf) * 64 + c4);
        }
        ld[it] = v;
    }
}

__device__ __forceinline__ void write_stage(unsigned short* __restrict__ xb,
                                            int tid, const float4* ld) {
#pragma unroll
    for (int it = 0; it < 5; ++it) {
        int idx = it * 256 + tid;
        if (idx < NFR * 16) {
            int j  = idx >> 4;
            int c4 = (idx & 15) << 2;
            u16x4 pk;
            pk[0] = f2bf(ld[it].x); pk[1] = f2bf(ld[it].y);
            pk[2] = f2bf(ld[it].z); pk[3] = f2bf(ld[it].w);
            *(u16x4*)(xb + j * XSTRIDE + c4) = pk;
        }
    }
}

__global__ __launch_bounds__(256, 2) void lu_main_kernel(
        const float* __restrict__ x,
        const unsigned short* __restrict__ bp,
        const float* __restrict__ bias,
        const float* __restrict__ iw,
        const float* __restrict__ ck,
        float* __restrict__ out) {
    __shared__ __align__(16) unsigned short xl[2 * NFR * XSTRIDE]; // 19,296 B
    __shared__ __align__(16) float sl[128 * 64];                   // 32,768 B

    const int bid  = blockIdx.x;
    const int tid  = threadIdx.x;
    const int lane = tid & 63;
    const int wv   = tid >> 6;          // wave = n-tile (16 filters)

    // ---- B fragments (kept in VGPRs for all chunks) ----
    bf16x8 Be[6], Bo[8];
#pragma unroll
    for (int ks = 0; ks < 6; ++ks)
        Be[ks] = __builtin_bit_cast(bf16x8,
            *(const u16x8*)(bp + (((size_t)(ks * 4 + wv)) * 64 + lane) * 8));
#pragma unroll
    for (int ks = 0; ks < 8; ++ks)
        Bo[ks] = __builtin_bit_cast(bf16x8,
            *(const u16x8*)(bp + (((size_t)(24 + ks * 4 + wv)) * 64 + lane) * 8));
    const int   fvar   = (wv << 4) + (lane & 15);
    const float bias_f = bias[fvar];

    // ---- prologue: stage chunk bid into xl[0] ----
    float4 ld[5];
    issue_loads(x, bid, tid, ld);
    write_stage(xl, tid, ld);
    __syncthreads();

    const int arow = lane & 15;
    const int ac0  = (lane >> 4) << 3;
    int cur = 0;

    for (int ci = 0; ci < CPB; ++ci) {
        const int g  = bid + ci * GRID;     // chunk id 0..2047
        const int b  = g >> 8;
        const bool have_next = (ci < CPB - 1);

        // A: issue next chunk's global loads (in flight across compute)
        if (have_next) issue_loads(x, g + GRID, tid, ld);

        // B: compute accumulators from xl[cur]
        const unsigned short* xc = xl + cur * (NFR * XSTRIDE);
        f32x4 accE[4], accO[4];
#pragma unroll
        for (int rt = 0; rt < 4; ++rt) {
            bf16x8 Af[4][2];
#pragma unroll
            for (int tap = 0; tap < 4; ++tap)
#pragma unroll
                for (int h = 0; h < 2; ++h) {
                    int row = (rt << 4) + arow + tap;
                    Af[tap][h] = __builtin_bit_cast(bf16x8,
                        *(const u16x8*)(xc + row * XSTRIDE + (h << 5) + ac0));
                }
            f32x4 ae = {0.f, 0.f, 0.f, 0.f};
#pragma unroll
            for (int ks = 0; ks < 6; ++ks)
                ae = __builtin_amdgcn_mfma_f32_16x16x32_bf16(
                        Af[ks >> 1][ks & 1], Be[ks], ae, 0, 0, 0);
            f32x4 ao = {0.f, 0.f, 0.f, 0.f};
#pragma unroll
            for (int ks = 0; ks < 8; ++ks)
                ao = __builtin_amdgcn_mfma_f32_16x16x32_bf16(
                        Af[ks >> 1][ks & 1], Bo[ks], ao, 0, 0, 0);
            accE[rt] = ae; accO[rt] = ao;
        }

        __syncthreads();   // xl[cur] free; prev flush's LDS reads drained

        // E: scatter accumulators -> sl (swizzled; 2-way max = free)
#pragma unroll
        for (int rt = 0; rt < 4; ++rt)
#pragma unroll
            for (int i = 0; i < 4; ++i) {
                int tl = (rt << 4) + ((lane >> 4) << 2) + i;
#pragma unroll
                for (int ph = 0; ph < 2; ++ph) {
                    float v = (ph ? accO[rt][i] : accE[rt][i]) + bias_f;
                    v = v >= 0.f ? v : 0.3f * v;
                    int fr = (tl << 1) + ph;
                    int uu = fvar >> 2;
                    int g2 = (fr >> 3) & 3;
                    sl[fr * 64 + (((uu ^ (g2 << 2)) << 2) | (fvar & 3))] = v;
                }
            }

        // D: cvt + write next chunk's frames into the other xl buffer
        if (have_next) write_stage(xl + (cur ^ 1) * (NFR * XSTRIDE), tid, ld);

        // F: exact fixup of output frames 0,1 of this batch (chunk 0 only)
        if ((g & 255) == 0) {
            __syncthreads();
            if (tid < 128) {
                int p = tid >> 6;
                int f = tid & 63;
                float acc = 0.f;
                for (int c = 0; c < 64; ++c) {
                    float x0 = x[(size_t)b * T_ * 64 + 0 * 64 + c];
                    float x1 = x[(size_t)b * T_ * 64 + 1 * 64 + c];
                    float w  = sigmoidf_(iw[c]);
                    float bl0 = w * x0 + (1.f - w) * x1;
                    if (p == 0) {
                        acc += ck[(2 * 64 + c) * 64 + f] * x0
                             + ck[(3 * 64 + c) * 64 + f] * bl0
                             + ck[(4 * 64 + c) * 64 + f] * x1;
                    } else {
                        float x2 = x[(size_t)b * T_ * 64 + 2 * 64 + c];
                        float bl1 = w * x1 + (1.f - w) * x2;
                        acc += ck[(1 * 64 + c) * 64 + f] * x0
                             + ck[(2 * 64 + c) * 64 + f] * bl0
                             + ck[(3 * 64 + c) * 64 + f] * x1
                             + ck[(4 * 64 + c) * 64 + f] * bl1;
                    }
                }
                acc += bias[f];
                acc = acc >= 0.f ? acc : 0.3f * acc;
                sl[p * 64 + f] = acc;   // g2==0 -> unswizzled
            }
        }

        __syncthreads();   // sl ready; xl[cur^1] ready

        // H: flush sl -> out, fully coalesced dwordx4 (1KB per wave-instr)
        {
            size_t obase = (size_t)b * TWO_T + (size_t)(g & 255) * 128;
#pragma unroll
            for (int it = 0; it < 8; ++it) {
                int idx = it * 256 + tid;
                int fr  = idx >> 4;
                int u   = idx & 15;
                int g2  = (fr >> 3) & 3;
                float4 v = *(const float4*)(sl + fr * 64 + ((u ^ (g2 << 2)) << 2));
                *(float4*)(out + (obase + fr) * 64 + (u << 2)) = v;
            }
        }

        cur ^= 1;
    }
}

extern "C" void kernel_launch(void* const* d_in, const int* in_sizes, int n_in,
                              void* d_out, int out_size, void* d_ws, size_t ws_size,
                              hipStream_t stream) {
    (void)in_sizes; (void)n_in; (void)out_size; (void)ws_size;
    const float* x    = (const float*)d_in[0];
    const float* iw   = (const float*)d_in[1];
    const float* ck   = (const float*)d_in[2];
    const float* bias = (const float*)d_in[3];
    float* out = (float*)d_out;
    unsigned short* bp = (unsigned short*)d_ws;   // needs 57,344 B

    lu_prep_kernel<<<56, 64, 0, stream>>>(iw, ck, bp);
    lu_main_kernel<<<GRID, 256, 0, stream>>>(x, bp, bias, iw, ck, out);
}

// Round 3
// 39.845 us; speedup vs baseline: 3.0646x; 3.0646x over previous
//
#include <hip/hip_runtime.h>
#include <hip/hip_bf16.h>
#include <cstdint>

// LearnableUpsamplingLayer: polyphase decomposition + bf16 MFMA.
// B=8, T=16384, C=64, F=64, filter=5, leaky 0.3.
// out[b,2t+p,f] = sum_tap M_p[tap][c,f] * x[t-1+tap, c]   (x outside [0,T) = 0)
// Even p=0: 3 taps; odd p=1: 4 taps. Frames 0,1 need a correction (the
// polyphase substitution leaks a (1-w)*x[0] term through blend[-1]): we
// precompute corr[b][p][f] in the prep kernel and subtract pre-activation.
//
// R3 design: NO __syncthreads anywhere. Each wave is fully independent:
// it stages its own 19-frame window (bf16) into a private LDS slice
// (ds_write -> ds_read ordered by lgkmcnt within the wave), runs 14 MFMA,
// applies bias+leaky, stores. 8192 blocks x 4 independent waves.

#define T_ 16384
#define TWO_T 32768
#define WSLICE 1376        // ushorts per wave slice (19*72=1368, pad to 16B mult)
#define XSTRIDE 72         // ushorts per frame row (144B; 2-way bank alias = free)

typedef __bf16 bf16x8 __attribute__((ext_vector_type(8)));
typedef float  f32x4  __attribute__((ext_vector_type(4)));
typedef unsigned short u16x8 __attribute__((ext_vector_type(8)));
typedef unsigned short u16x4 __attribute__((ext_vector_type(4)));

__device__ __forceinline__ unsigned short f2bf(float f) {
    union { float f; uint32_t u; } v; v.f = f;
    uint32_t u = v.u;
    return (unsigned short)((u + 0x7FFFu + ((u >> 16) & 1u)) >> 16);
}

__device__ __forceinline__ float sigmoidf_(float z) {
    return 1.0f / (1.0f + expf(-z));
}

// ---------------- prep: 64 blocks x 64 threads.
// Blocks 0..55: build the 7 polyphase matrices as packed bf16 MFMA B-fragments.
//   Fragment (phase, ks, nt): lane l, elem i holds
//   M[tap=ks>>1][c=(ks&1)*32+(l>>4)*8+i][n=nt*16+(l&15)].
// Blocks 56..63: b = fi-56; corr[b][p][f] = sum_c K[1-p][c][f]*(1-w_c)*x[b,0,c]
__global__ void lu_prep_kernel(const float* __restrict__ iw,
                               const float* __restrict__ ck,
                               const float* __restrict__ x,
                               unsigned short* __restrict__ bp,
                               float* __restrict__ corrf) {
    int fi = blockIdx.x;
    int l  = threadIdx.x;
    if (fi < 56) {
        int phase, ks, nt;
        if (fi < 24) { phase = 0; ks = fi >> 2; nt = fi & 3; }
        else         { phase = 1; ks = (fi - 24) >> 2; nt = (fi - 24) & 3; }
        int tap = ks >> 1;
        int n   = nt * 16 + (l & 15);
        int c0  = ((ks & 1) << 5) + ((l >> 4) << 3);
        u16x8 pk;
#pragma unroll
        for (int i = 0; i < 8; ++i) {
            int c = c0 + i;
            float w = sigmoidf_(iw[c]);
            float v;
            #define CK(k) ck[((k) * 64 + c) * 64 + n]
            if (phase == 0) {
                if (tap == 0)      v = CK(0) + w * CK(1);
                else if (tap == 1) v = (1.f - w) * CK(1) + CK(2) + w * CK(3);
                else               v = (1.f - w) * CK(3) + CK(4);
            } else {
                if (tap == 0)      v = w * CK(0);
                else if (tap == 1) v = (1.f - w) * CK(0) + CK(1) + w * CK(2);
                else if (tap == 2) v = (1.f - w) * CK(2) + CK(3) + w * CK(4);
                else               v = (1.f - w) * CK(4);
            }
            #undef CK
            pk[i] = f2bf(v);
        }
        *(u16x8*)(bp + (((size_t)fi * 64) + l) * 8) = pk;
    } else {
        int b = fi - 56;
        int f = l;
        float cE = 0.f, cO = 0.f;
        for (int c = 0; c < 64; ++c) {
            float w = sigmoidf_(iw[c]);
            float g = (1.f - w) * x[(size_t)b * T_ * 64 + c];
            cE += ck[(64 + c) * 64 + f] * g;   // K1
            cO += ck[c * 64 + f] * g;          // K0
        }
        corrf[b * 128 + f]      = cE;
        corrf[b * 128 + 64 + f] = cO;
    }
}

// ---------------- main kernel: one 16-time-pair window per block,
// wave wv handles filter tile nt = wv. No barriers, waves independent.
__global__ __launch_bounds__(256) void lu_main_kernel(
        const float* __restrict__ x,
        const unsigned short* __restrict__ bp,
        const float* __restrict__ corrf,
        const float* __restrict__ bias,
        float* __restrict__ out) {
    __shared__ __align__(16) unsigned short xl[4][WSLICE];

    const int wid  = blockIdx.x;        // 0..8191
    const int b    = wid >> 10;         // batch
    const int win  = wid & 1023;        // window within batch
    const int tw0  = win << 4;          // first time-pair of window
    const int tid  = threadIdx.x;
    const int lane = tid & 63;
    const int wv   = tid >> 6;          // wave = filter tile nt

    unsigned short* xw = &xl[wv][0];

    // ---- stage x[tw0-1 .. tw0+17] as bf16 into this wave's LDS slice ----
#pragma unroll
    for (int it = 0; it < 5; ++it) {
        int idx = it * 64 + lane;       // 0..319; need 304
        if (idx < 304) {
            int j  = idx >> 4;          // frame 0..18
            int c4 = (idx & 15) << 2;
            int gf = tw0 - 1 + j;
            float4 v = make_float4(0.f, 0.f, 0.f, 0.f);
            if (gf >= 0 && gf < T_)
                v = *(const float4*)(x + ((size_t)b * T_ + gf) * 64 + c4);
            u16x4 pk;
            pk[0] = f2bf(v.x); pk[1] = f2bf(v.y);
            pk[2] = f2bf(v.z); pk[3] = f2bf(v.w);
            *(u16x4*)(xw + j * XSTRIDE + c4) = pk;
        }
    }

    // ---- B fragments for this wave's filter tile ----
    bf16x8 Be[6], Bo[8];
#pragma unroll
    for (int ks = 0; ks < 6; ++ks)
        Be[ks] = __builtin_bit_cast(bf16x8,
            *(const u16x8*)(bp + (((size_t)(ks * 4 + wv)) * 64 + lane) * 8));
#pragma unroll
    for (int ks = 0; ks < 8; ++ks)
        Bo[ks] = __builtin_bit_cast(bf16x8,
            *(const u16x8*)(bp + (((size_t)(24 + ks * 4 + wv)) * 64 + lane) * 8));

    const int   f      = (wv << 4) + (lane & 15);
    const float bias_f = bias[f];
    const int   arow   = lane & 15;
    const int   ac0    = (lane >> 4) << 3;

    // ---- A fragments from own LDS slice (lgkmcnt orders vs the writes) ----
    bf16x8 Af[4][2];
#pragma unroll
    for (int tap = 0; tap < 4; ++tap)
#pragma unroll
        for (int h = 0; h < 2; ++h)
            Af[tap][h] = __builtin_bit_cast(bf16x8,
                *(const u16x8*)(xw + (arow + tap) * XSTRIDE + (h << 5) + ac0));

    // ---- 14 MFMA ----
    f32x4 accE = {0.f, 0.f, 0.f, 0.f};
#pragma unroll
    for (int ks = 0; ks < 6; ++ks)
        accE = __builtin_amdgcn_mfma_f32_16x16x32_bf16(
                Af[ks >> 1][ks & 1], Be[ks], accE, 0, 0, 0);
    f32x4 accO = {0.f, 0.f, 0.f, 0.f};
#pragma unroll
    for (int ks = 0; ks < 8; ++ks)
        accO = __builtin_amdgcn_mfma_f32_16x16x32_bf16(
                Af[ks >> 1][ks & 1], Bo[ks], accO, 0, 0, 0);

    // ---- boundary correction for output frames 0,1 (t=0 windows only) ----
    if (win == 0) {
        float cE = corrf[b * 128 + f];
        float cO = corrf[b * 128 + 64 + f];
        if ((lane >> 4) == 0) {
            accE[0] -= cE;
            accO[0] -= cO;
        }
    }

    // ---- epilogue: bias + leaky_relu + stores (64B-line granular) ----
    const size_t ob = ((size_t)b * TWO_T + ((size_t)tw0 << 1)) * 64 + f;
#pragma unroll
    for (int i = 0; i < 4; ++i) {
        int r2 = (((lane >> 4) << 2) + i) << 1;
        float vE = accE[i] + bias_f;
        vE = vE >= 0.f ? vE : 0.3f * vE;
        out[ob + (size_t)r2 * 64] = vE;
        float vO = accO[i] + bias_f;
        vO = vO >= 0.f ? vO : 0.3f * vO;
        out[ob + (size_t)(r2 + 1) * 64] = vO;
    }
}

extern "C" void kernel_launch(void* const* d_in, const int* in_sizes, int n_in,
                              void* d_out, int out_size, void* d_ws, size_t ws_size,
                              hipStream_t stream) {
    (void)in_sizes; (void)n_in; (void)out_size; (void)ws_size;
    const float* x    = (const float*)d_in[0];
    const float* iw   = (const float*)d_in[1];
    const float* ck   = (const float*)d_in[2];
    const float* bias = (const float*)d_in[3];
    float* out = (float*)d_out;
    unsigned short* bp = (unsigned short*)d_ws;            // 57,344 B
    float* corrf = (float*)((char*)d_ws + 57344);          // 4,096 B

    lu_prep_kernel<<<64, 64, 0, stream>>>(iw, ck, x, bp, corrf);
    lu_main_kernel<<<8192, 256, 0, stream>>>(x, bp, corrf, bias, out);
}

// Round 4
// 32.331 us; speedup vs baseline: 3.7768x; 1.2324x over previous
//
#include <hip/hip_runtime.h>
#include <hip/hip_bf16.h>
#include <cstdint>

// LearnableUpsamplingLayer: polyphase decomposition + bf16 MFMA.
// B=8, T=16384, C=64, F=64, filter=5, leaky 0.3.
// out[b,2t+p,f] = sum_tap M_p[tap][c,f] * x[t-1+tap, c]   (x outside [0,T) = 0)
// Even p=0: 3 taps; odd p=1: 4 taps. Frames 0,1 need a correction (the
// polyphase substitution leaks a (1-w)*x[0] term through blend[-1]):
// corr[b][p][f] precomputed in prep, subtracted pre-activation.
//
// R4: independent waves (no barriers), but each wave owns 4 consecutive
// 16-pair windows: B-fragments loaded ONCE per wave (amortized), windows
// software-pipelined (prefetch w+1 global loads during w compute).
// Native bf16 casts (v_cvt_pk_bf16_f32) instead of hand-rolled rounding.

#define T_ 16384
#define TWO_T 32768
#define XSTRIDE 72         // ushorts per frame row (144B; benign 2-way alias)
#define WSL 1376           // ushorts per wave slice (19*72=1368, pad to 16B)

typedef __bf16 bf16x8 __attribute__((ext_vector_type(8)));
typedef __bf16 bf16x4 __attribute__((ext_vector_type(4)));
typedef float  f32x4  __attribute__((ext_vector_type(4)));
typedef unsigned short u16x8 __attribute__((ext_vector_type(8)));

__device__ __forceinline__ float sigmoidf_(float z) {
    return 1.0f / (1.0f + expf(-z));
}

__device__ __forceinline__ unsigned short f2bf(float f) {
    union { float f; uint32_t u; } v; v.f = f;
    uint32_t u = v.u;
    return (unsigned short)((u + 0x7FFFu + ((u >> 16) & 1u)) >> 16);
}

// ---------------- prep: 64 blocks x 64 threads.
// Blocks 0..55: the 7 polyphase matrices as packed bf16 MFMA B-fragments.
//   Fragment (phase, ks, nt): lane l elem i holds
//   M[tap=ks>>1][c=(ks&1)*32+(l>>4)*8+i][n=nt*16+(l&15)].
// Blocks 56..63: b = fi-56; corr[b][{E,O}][f] = sum_c K[{1,0}][c][f]*(1-w_c)*x[b,0,c]
__global__ void lu_prep_kernel(const float* __restrict__ iw,
                               const float* __restrict__ ck,
                               const float* __restrict__ x,
                               unsigned short* __restrict__ bp,
                               float* __restrict__ corrf) {
    int fi = blockIdx.x;
    int l  = threadIdx.x;
    if (fi < 56) {
        int phase, ks, nt;
        if (fi < 24) { phase = 0; ks = fi >> 2; nt = fi & 3; }
        else         { phase = 1; ks = (fi - 24) >> 2; nt = (fi - 24) & 3; }
        int tap = ks >> 1;
        int n   = nt * 16 + (l & 15);
        int c0  = ((ks & 1) << 5) + ((l >> 4) << 3);
        u16x8 pk;
#pragma unroll
        for (int i = 0; i < 8; ++i) {
            int c = c0 + i;
            float w = sigmoidf_(iw[c]);
            float v;
            #define CK(k) ck[((k) * 64 + c) * 64 + n]
            if (phase == 0) {
                if (tap == 0)      v = CK(0) + w * CK(1);
                else if (tap == 1) v = (1.f - w) * CK(1) + CK(2) + w * CK(3);
                else               v = (1.f - w) * CK(3) + CK(4);
            } else {
                if (tap == 0)      v = w * CK(0);
                else if (tap == 1) v = (1.f - w) * CK(0) + CK(1) + w * CK(2);
                else if (tap == 2) v = (1.f - w) * CK(2) + CK(3) + w * CK(4);
                else               v = (1.f - w) * CK(4);
            }
            #undef CK
            pk[i] = f2bf(v);
        }
        *(u16x8*)(bp + (((size_t)fi * 64) + l) * 8) = pk;
    } else {
        int b = fi - 56;
        int f = l;
        float cE = 0.f, cO = 0.f;
#pragma unroll
        for (int c = 0; c < 64; ++c) {
            float w = sigmoidf_(iw[c]);
            float g = (1.f - w) * x[(size_t)b * T_ * 64 + c];
            cE += ck[(64 + c) * 64 + f] * g;   // K1
            cO += ck[c * 64 + f] * g;          // K0
        }
        corrf[b * 128 + f]      = cE;
        corrf[b * 128 + 64 + f] = cO;
    }
}

// ---------------- main ----------------
__device__ __forceinline__ void issue_loads(const float* __restrict__ x,
                                            int b, int t0, int lane, float4* ld) {
#pragma unroll
    for (int it = 0; it < 5; ++it) {
        int idx = it * 64 + lane;       // 0..319, need 304
        int j   = idx >> 4;             // frame 0..18
        int c4  = (idx & 15) << 2;
        int gf  = t0 - 1 + j;
        float4 v = make_float4(0.f, 0.f, 0.f, 0.f);
        if (idx < 304 && gf >= 0 && gf < T_)
            v = *(const float4*)(x + ((size_t)b * T_ + gf) * 64 + c4);
        ld[it] = v;
    }
}

__global__ __launch_bounds__(256, 4) void lu_main_kernel(
        const float* __restrict__ x,
        const unsigned short* __restrict__ bp,
        const float* __restrict__ corrf,
        const float* __restrict__ bias,
        float* __restrict__ out) {
    __shared__ __align__(16) unsigned short xl[4][WSL];   // 11,008 B

    const int bid  = blockIdx.x;        // 0..2047: (batch, quad)
    const int b    = bid >> 8;
    const int p0   = (bid & 255) << 6;  // first time-pair of this quad (64 pairs)
    const int tid  = threadIdx.x;
    const int lane = tid & 63;
    const int wv   = tid >> 6;          // wave = filter tile

    unsigned short* xw = &xl[wv][0];

    // ---- prefetch window 0 ----
    float4 ld[5];
    issue_loads(x, b, p0, lane, ld);

    // ---- B fragments for this wave's filter tile (loaded once) ----
    bf16x8 Be[6], Bo[8];
#pragma unroll
    for (int ks = 0; ks < 6; ++ks)
        Be[ks] = __builtin_bit_cast(bf16x8,
            *(const u16x8*)(bp + (((size_t)(ks * 4 + wv)) * 64 + lane) * 8));
#pragma unroll
    for (int ks = 0; ks < 8; ++ks)
        Bo[ks] = __builtin_bit_cast(bf16x8,
            *(const u16x8*)(bp + (((size_t)(24 + ks * 4 + wv)) * 64 + lane) * 8));

    const int   f      = (wv << 4) + (lane & 15);
    const float bias_f = bias[f];
    const int   arow   = lane & 15;
    const int   hi     = lane >> 4;
    const int   ac0    = hi << 3;

    for (int w = 0; w < 4; ++w) {
        const int t0 = p0 + (w << 4);

        // ---- cvt + ds_write window w (native bf16 casts -> cvt_pk) ----
#pragma unroll
        for (int it = 0; it < 5; ++it) {
            int idx = it * 64 + lane;
            if (idx < 304) {
                int j  = idx >> 4;
                int c4 = (idx & 15) << 2;
                bf16x4 pk;
                pk[0] = (__bf16)ld[it].x; pk[1] = (__bf16)ld[it].y;
                pk[2] = (__bf16)ld[it].z; pk[3] = (__bf16)ld[it].w;
                *(bf16x4*)(xw + j * XSTRIDE + c4) = pk;
            }
        }

        // ---- prefetch window w+1 (in flight across compute below) ----
        if (w < 3) issue_loads(x, b, p0 + ((w + 1) << 4), lane, ld);

        // ---- A reads interleaved with 14 MFMA (E and O share A-frags) ----
        f32x4 accE = {0.f, 0.f, 0.f, 0.f};
        f32x4 accO = {0.f, 0.f, 0.f, 0.f};
#pragma unroll
        for (int tap = 0; tap < 4; ++tap)
#pragma unroll
            for (int h = 0; h < 2; ++h) {
                bf16x8 a = __builtin_bit_cast(bf16x8,
                    *(const u16x8*)(xw + (arow + tap) * XSTRIDE + (h << 5) + ac0));
                int ks = tap * 2 + h;
                if (tap < 3)
                    accE = __builtin_amdgcn_mfma_f32_16x16x32_bf16(a, Be[ks], accE, 0, 0, 0);
                accO = __builtin_amdgcn_mfma_f32_16x16x32_bf16(a, Bo[ks], accO, 0, 0, 0);
            }

        // ---- boundary correction (output frames 0,1 of each batch) ----
        if (((bid & 255) | w) == 0 && hi == 0) {
            accE[0] -= corrf[b * 128 + f];
            accO[0] -= corrf[b * 128 + 64 + f];
        }

        // ---- epilogue: bias + leaky_relu + stores ----
        const size_t ob = ((size_t)b * TWO_T + ((size_t)t0 << 1)) * 64 + f;
#pragma unroll
        for (int i = 0; i < 4; ++i) {
            int r2 = ((hi << 2) + i) << 1;
            float vE = accE[i] + bias_f;
            vE = vE >= 0.f ? vE : 0.3f * vE;
            out[ob + (size_t)r2 * 64] = vE;
            float vO = accO[i] + bias_f;
            vO = vO >= 0.f ? vO : 0.3f * vO;
            out[ob + (size_t)(r2 + 1) * 64] = vO;
        }
    }
}

extern "C" void kernel_launch(void* const* d_in, const int* in_sizes, int n_in,
                              void* d_out, int out_size, void* d_ws, size_t ws_size,
                              hipStream_t stream) {
    (void)in_sizes; (void)n_in; (void)out_size; (void)ws_size;
    const float* x    = (const float*)d_in[0];
    const float* iw   = (const float*)d_in[1];
    const float* ck   = (const float*)d_in[2];
    const float* bias = (const float*)d_in[3];
    float* out = (float*)d_out;
    unsigned short* bp = (unsigned short*)d_ws;            // 57,344 B
    float* corrf = (float*)((char*)d_ws + 57344);          // 4,096 B

    lu_prep_kernel<<<64, 64, 0, stream>>>(iw, ck, x, bp, corrf);
    lu_main_kernel<<<2048, 256, 0, stream>>>(x, bp, corrf, bias, out);
}